// Round 6
// baseline (441.725 us; speedup 1.0000x reference)
//
#include <hip/hip_runtime.h>
#include <hip/hip_cooperative_groups.h>

namespace cg = cooperative_groups;

// Caps_BN: BatchNorm2d (training stats, affine=False) + grouped 1x1 conv (16 caps
// of 32x32) + bias, folded: out = (W*rstd) @ x + (bias - (W*rstd) @ mean).
// x (64, 512, 32, 32) f32. Single cooperative kernel, 3 phases, 2 grid.syncs.
//
// ws layout (floats):
//   [1024, 17408)   W' folded weight (c, o, i)
//   [17408, 17920)  b' folded bias (c, o)
//   [17920, 20992)  per-quarter channel partials: [j][ch][{s,ss}], j=0..2
//
// Lessons encoded:
//  - per-thread state must stay <= ~64 floats or it spills (R2/R3/R4: VGPR_Count
//    40-256 + WRITE_SIZE 1.5-2.9x = scratch traffic). Clean shape: xv[32] +
//    streamed per-o acc (R1/R5, WRITE exactly 1.0x).
//  - dependent 32-FMA chain halves VALU issue (R1, 50% VALUBusy) -> 4 partials.
//  - scalar 4B/lane loads/stores measured clean; nt stores keep out from
//    evicting L3-resident x (hypothesis still under test; FETCH_SIZE next
//    round is the verdict: ~262MB = no L3 help, ~150MB = L3 working).

#define GRID_BLKS 1536
#define NELEM_PER_CH 65536.0f
#define WS_WP   1024
#define WS_BP   17408
#define WS_PART 17920

__global__ __launch_bounds__(256, 6) void caps_all(const float* __restrict__ x,
                                                   const float* __restrict__ w,
                                                   const float* __restrict__ bias,
                                                   float* __restrict__ out,
                                                   float* __restrict__ ws) {
    const int b = blockIdx.x;
    const int t = threadIdx.x;
    cg::grid_group grid = cg::this_grid();

    // ---- phase 1: per-channel partial sums; 3 blocks per channel ----
    {
        const int ch = b & 511;
        const int j  = b >> 9;                       // 0..2
        const int n0 = (j == 0) ? 0 : (22 + 21 * (j - 1));
        const int n1 = (j == 0) ? 22 : (n0 + 21);
        const float4* __restrict__ x4 = (const float4*)x;
        float s = 0.f, ss = 0.f;
        for (int n = n0; n < n1; ++n) {
            float4 v = x4[((size_t)n * 512 + ch) * 256 + t];
            s  += v.x + v.y + v.z + v.w;
            ss += v.x * v.x + v.y * v.y + v.z * v.z + v.w * v.w;
        }
#pragma unroll
        for (int off = 32; off > 0; off >>= 1) {
            s  += __shfl_down(s, off);
            ss += __shfl_down(ss, off);
        }
        __shared__ float red[4][2];
        if ((t & 63) == 0) { red[t >> 6][0] = s; red[t >> 6][1] = ss; }
        __syncthreads();
        if (t == 0) {
            float S = 0.f, SS = 0.f;
#pragma unroll
            for (int k = 0; k < 4; ++k) { S += red[k][0]; SS += red[k][1]; }
            ws[WS_PART + j * 1024 + ch * 2 + 0] = S;
            ws[WS_PART + j * 1024 + ch * 2 + 1] = SS;
        }
    }
    grid.sync();

    // ---- phase 2: finalize stats + fold weight/bias (blocks 0..63) ----
    if (b < 64) {
        const int c  = b >> 2;
        const int o  = (b & 3) * 8 + (t >> 5);
        const int i  = t & 31;
        const int ch = c * 32 + i;
        float S = 0.f, SS = 0.f;
#pragma unroll
        for (int j = 0; j < 3; ++j) {
            S  += ws[WS_PART + j * 1024 + ch * 2 + 0];
            SS += ws[WS_PART + j * 1024 + ch * 2 + 1];
        }
        const float mean = S / NELEM_PER_CH;
        const float rstd = rsqrtf(SS / NELEM_PER_CH - mean * mean + 1e-5f);
        const float wv = w[c * 1024 + o * 32 + i] * rstd;
        ws[WS_WP + c * 1024 + o * 32 + i] = wv;       // W'[c][o][i]
        float prod = wv * mean;
#pragma unroll
        for (int off = 16; off > 0; off >>= 1) prod += __shfl_xor(prod, off);
        if (i == 0) ws[WS_BP + c * 32 + o] = bias[c * 32 + o] - prod;
    }
    grid.sync();

    // ---- phase 3: main transform, grid-stride over 4096 (q,c,n) tiles ----
    for (int tile = b; tile < 4096; tile += GRID_BLKS) {
        const int q = tile & 3, c = (tile >> 2) & 15, n = tile >> 6;
        const int hw = q * 256 + t;
        const size_t base = (((size_t)n * 16 + c) * 32) * 1024 + hw;
        const float* __restrict__ Wc = ws + WS_WP + c * 1024;   // block-uniform
        const float* __restrict__ b2 = ws + WS_BP + c * 32;

        float xv[32];
#pragma unroll
        for (int i = 0; i < 32; ++i) xv[i] = x[base + (size_t)i * 1024];

#pragma unroll 4
        for (int o = 0; o < 32; ++o) {
            const float* __restrict__ wr = Wc + o * 32;
            float p0 = 0.f, p1 = 0.f, p2 = 0.f, p3 = 0.f;
#pragma unroll
            for (int i = 0; i < 32; i += 4) {
                p0 += wr[i + 0] * xv[i + 0];
                p1 += wr[i + 1] * xv[i + 1];
                p2 += wr[i + 2] * xv[i + 2];
                p3 += wr[i + 3] * xv[i + 3];
            }
            __builtin_nontemporal_store(b2[o] + ((p0 + p1) + (p2 + p3)),
                                        out + base + (size_t)o * 1024);
        }
    }
}

// ---------------- fallback path (proven R5 kernels) ----------------
__global__ __launch_bounds__(256) void caps_stats(const float* __restrict__ x,
                                                  float* __restrict__ ws) {
    const int ch = blockIdx.x;
    const int tid = threadIdx.x;
    const float4* __restrict__ x4 = (const float4*)x;
    float s = 0.f, ss = 0.f;
#pragma unroll 4
    for (int n = 0; n < 64; ++n) {
        float4 v = x4[((size_t)n * 512 + ch) * 256 + tid];
        s  += v.x + v.y + v.z + v.w;
        ss += v.x * v.x + v.y * v.y + v.z * v.z + v.w * v.w;
    }
#pragma unroll
    for (int off = 32; off > 0; off >>= 1) {
        s  += __shfl_down(s, off);
        ss += __shfl_down(ss, off);
    }
    __shared__ float red[4][2];
    if ((tid & 63) == 0) { red[tid >> 6][0] = s; red[tid >> 6][1] = ss; }
    __syncthreads();
    if (tid == 0) {
        float S = 0.f, SS = 0.f;
#pragma unroll
        for (int k = 0; k < 4; ++k) { S += red[k][0]; SS += red[k][1]; }
        float mean = S / NELEM_PER_CH;
        float var = SS / NELEM_PER_CH - mean * mean;
        ws[0 + ch] = mean;
        ws[512 + ch] = rsqrtf(var + 1e-5f);
    }
}

__global__ __launch_bounds__(1024) void caps_fold(const float* __restrict__ w,
                                                  const float* __restrict__ bias,
                                                  float* __restrict__ ws) {
    const int c = blockIdx.x;
    const int t = threadIdx.x;
    const int o = t >> 5;
    const int i = t & 31;
    const float mean = ws[c * 32 + i];
    const float rstd = ws[512 + c * 32 + i];
    const float wv = w[c * 1024 + t] * rstd;
    ws[WS_WP + c * 1024 + t] = wv;
    float prod = wv * mean;
#pragma unroll
    for (int off = 16; off > 0; off >>= 1) prod += __shfl_xor(prod, off);
    if (i == 0) ws[WS_BP + c * 32 + o] = bias[c * 32 + o] - prod;
}

__global__ __launch_bounds__(256) void caps_main(const float* __restrict__ x,
                                                 const float* __restrict__ ws,
                                                 float* __restrict__ out) {
    const int hw = blockIdx.x * 256 + threadIdx.x;
    const int c = blockIdx.y;
    const int n = blockIdx.z;
    const size_t base = (((size_t)n * 16 + c) * 32) * 1024 + hw;
    const float* __restrict__ Wc = ws + WS_WP + c * 1024;
    const float* __restrict__ b2 = ws + WS_BP + c * 32;
    float xv[32];
#pragma unroll
    for (int i = 0; i < 32; ++i) xv[i] = x[base + (size_t)i * 1024];
#pragma unroll 4
    for (int o = 0; o < 32; ++o) {
        const float* __restrict__ wr = Wc + o * 32;
        float p0 = 0.f, p1 = 0.f, p2 = 0.f, p3 = 0.f;
#pragma unroll
        for (int i = 0; i < 32; i += 4) {
            p0 += wr[i + 0] * xv[i + 0];
            p1 += wr[i + 1] * xv[i + 1];
            p2 += wr[i + 2] * xv[i + 2];
            p3 += wr[i + 3] * xv[i + 3];
        }
        __builtin_nontemporal_store(b2[o] + ((p0 + p1) + (p2 + p3)),
                                    out + base + (size_t)o * 1024);
    }
}

extern "C" void kernel_launch(void* const* d_in, const int* in_sizes, int n_in,
                              void* d_out, int out_size, void* d_ws, size_t ws_size,
                              hipStream_t stream) {
    const float* x    = (const float*)d_in[0];
    const float* w    = (const float*)d_in[1];
    const float* bias = (const float*)d_in[2];
    float* out = (float*)d_out;
    float* ws  = (float*)d_ws;

    void* args[] = {(void*)&x, (void*)&w, (void*)&bias, (void*)&out, (void*)&ws};
    hipError_t err = hipLaunchCooperativeKernel((const void*)caps_all,
                                                dim3(GRID_BLKS), dim3(256),
                                                args, 0, stream);
    if (err != hipSuccess) {
        // fallback: proven 3-kernel path (R5, 74.8 us)
        caps_stats<<<512, 256, 0, stream>>>(x, ws);
        caps_fold<<<16, 1024, 0, stream>>>(w, bias, ws);
        caps_main<<<dim3(4, 16, 64), 256, 0, stream>>>(x, ws, out);
    }
}

// Round 9
// 350.623 us; speedup vs baseline: 1.2598x; 1.2598x over previous
//
#include <hip/hip_runtime.h>

// Caps_BN: BatchNorm2d (training stats, affine=False) + grouped 1x1 conv (16 caps
// of 32x32) + bias, folded: out = (W*rstd) @ x + (bias - (W*rstd) @ mean).
// x (64, 512, 32, 32) f32.
//
// Fused persistent kernel with a SOFTWARE global barrier (atomics + fences).
// R8 lesson: cooperative launch + grid.sync() is NOT graph-capture-safe on this
// stack (first call passed, graph replays raced -> absmax 5.44). The software
// barrier is self-contained: bar_init zeroes counters every kernel_launch, so
// replays are deterministic; residency is proven via the occupancy query before
// choosing the grid; the spin is bounded so nothing can hang.
//
// ws layout (floats):
//   [1024, 17408)   W' folded weight (c, o, i)
//   [17408, 17920)  b' folded bias (c, o)
//   [17920, 20992)  per-chunk channel partials: [j][ch][{s,ss}], j<J<=3
//   [20992, 21008)  barrier counters (as ints)
//
// Lessons encoded:
//  - NEVER set the min-waves arg of __launch_bounds__: (256,6) forced VGPR=40 +
//    scratch spills (R4 113us, R6 440us, VALUBusy 10%). Plain (256) = VGPR 52.
//  - R6: fused structure reads x from HBM exactly once (FETCH 131.7 MB);
//    phase 3 is 100% L3-served. HBM floor ~= 265 MB ~= 42 us.
//  - xv[32] + 4 independent partials is the proven spill-free, ILP-clean shape.
//  - scalar 4B/lane stores = exactly 1.0x WRITE_SIZE; nt stores protect L3.
//  - R8: no cg::grid_sync under graph capture. Software barrier + init kernel.

#define NELEM_PER_CH 65536.0f
#define WS_WP   1024
#define WS_BP   17408
#define WS_PART 17920
#define WS_BAR  20992

__global__ void bar_init(int* __restrict__ bar) {
    if (threadIdx.x < 16) bar[threadIdx.x] = 0;
}

__device__ __forceinline__ void gbarrier(int* __restrict__ bar, int slot, int target) {
    __syncthreads();
    __threadfence();                      // release: my ws writes visible device-wide
    if (threadIdx.x == 0) {
        atomicAdd(&bar[slot], 1);
        // bounded spin: 4M polls x s_sleep(8) ~= 0.9 s worst case, can't hang the
        // 600 s harness. If it ever trips, results fail validation visibly.
        int spins = 0;
        while (atomicAdd(&bar[slot], 0) < target && spins < (1 << 22)) {
            ++spins;
            __builtin_amdgcn_s_sleep(8);
        }
    }
    __syncthreads();                      // t0's observation ordered before block
    __threadfence();                      // acquire: drop stale cached lines
}

__global__ __launch_bounds__(256) void caps_all(const float* __restrict__ x,
                                                const float* __restrict__ w,
                                                const float* __restrict__ bias,
                                                float* __restrict__ out,
                                                float* __restrict__ ws,
                                                int* __restrict__ bar,
                                                int J, int G) {
    const int b = blockIdx.x;
    const int t = threadIdx.x;

    // ---- phase 1: per-channel partial sums; J blocks per channel ----
    {
        const int ch = b & 511;
        const int j  = b >> 9;                       // 0..J-1
        const int n0 = (64 * j) / J;
        const int n1 = (64 * (j + 1)) / J;
        const float4* __restrict__ x4 = (const float4*)x;
        float s = 0.f, ss = 0.f;
        for (int n = n0; n < n1; ++n) {
            float4 v = x4[((size_t)n * 512 + ch) * 256 + t];
            s  += v.x + v.y + v.z + v.w;
            ss += v.x * v.x + v.y * v.y + v.z * v.z + v.w * v.w;
        }
#pragma unroll
        for (int off = 32; off > 0; off >>= 1) {
            s  += __shfl_down(s, off);
            ss += __shfl_down(ss, off);
        }
        __shared__ float red[4][2];
        if ((t & 63) == 0) { red[t >> 6][0] = s; red[t >> 6][1] = ss; }
        __syncthreads();
        if (t == 0) {
            float S = 0.f, SS = 0.f;
#pragma unroll
            for (int k = 0; k < 4; ++k) { S += red[k][0]; SS += red[k][1]; }
            ws[WS_PART + j * 1024 + ch * 2 + 0] = S;
            ws[WS_PART + j * 1024 + ch * 2 + 1] = SS;
        }
    }
    gbarrier(bar, 0, G);

    // ---- phase 2: finalize stats + fold weight/bias (blocks 0..63) ----
    if (b < 64) {
        const int c  = b >> 2;
        const int o  = (b & 3) * 8 + (t >> 5);
        const int i  = t & 31;
        const int ch = c * 32 + i;
        float S = 0.f, SS = 0.f;
        for (int j = 0; j < J; ++j) {
            S  += ws[WS_PART + j * 1024 + ch * 2 + 0];
            SS += ws[WS_PART + j * 1024 + ch * 2 + 1];
        }
        const float mean = S / NELEM_PER_CH;
        const float rstd = rsqrtf(SS / NELEM_PER_CH - mean * mean + 1e-5f);
        const float wv = w[c * 1024 + o * 32 + i] * rstd;
        ws[WS_WP + c * 1024 + o * 32 + i] = wv;       // W'[c][o][i]
        float prod = wv * mean;
#pragma unroll
        for (int off = 16; off > 0; off >>= 1) prod += __shfl_xor(prod, off);
        if (i == 0) ws[WS_BP + c * 32 + o] = bias[c * 32 + o] - prod;
    }
    gbarrier(bar, 1, G);

    // ---- phase 3: main transform, grid-stride over 4096 (q,c,n) tiles ----
    for (int tile = b; tile < 4096; tile += G) {
        const int q = tile & 3, c = (tile >> 2) & 15, n = tile >> 6;
        const int hw = q * 256 + t;
        const size_t base = (((size_t)n * 16 + c) * 32) * 1024 + hw;
        const float* __restrict__ Wc = ws + WS_WP + c * 1024;   // block-uniform
        const float* __restrict__ b2 = ws + WS_BP + c * 32;

        float xv[32];
#pragma unroll
        for (int i = 0; i < 32; ++i) xv[i] = x[base + (size_t)i * 1024];

#pragma unroll 4
        for (int o = 0; o < 32; ++o) {
            const float* __restrict__ wr = Wc + o * 32;
            float p0 = 0.f, p1 = 0.f, p2 = 0.f, p3 = 0.f;
#pragma unroll
            for (int i = 0; i < 32; i += 4) {
                p0 += wr[i + 0] * xv[i + 0];
                p1 += wr[i + 1] * xv[i + 1];
                p2 += wr[i + 2] * xv[i + 2];
                p3 += wr[i + 3] * xv[i + 3];
            }
            __builtin_nontemporal_store(b2[o] + ((p0 + p1) + (p2 + p3)),
                                        out + base + (size_t)o * 1024);
        }
    }
}

// ---------------- fallback path (proven R5 kernels, 74.8 us) ----------------
__global__ __launch_bounds__(256) void caps_stats(const float* __restrict__ x,
                                                  float* __restrict__ ws) {
    const int ch = blockIdx.x;
    const int tid = threadIdx.x;
    const float4* __restrict__ x4 = (const float4*)x;
    float s = 0.f, ss = 0.f;
#pragma unroll 4
    for (int n = 0; n < 64; ++n) {
        float4 v = x4[((size_t)n * 512 + ch) * 256 + tid];
        s  += v.x + v.y + v.z + v.w;
        ss += v.x * v.x + v.y * v.y + v.z * v.z + v.w * v.w;
    }
#pragma unroll
    for (int off = 32; off > 0; off >>= 1) {
        s  += __shfl_down(s, off);
        ss += __shfl_down(ss, off);
    }
    __shared__ float red[4][2];
    if ((tid & 63) == 0) { red[tid >> 6][0] = s; red[tid >> 6][1] = ss; }
    __syncthreads();
    if (tid == 0) {
        float S = 0.f, SS = 0.f;
#pragma unroll
        for (int k = 0; k < 4; ++k) { S += red[k][0]; SS += red[k][1]; }
        float mean = S / NELEM_PER_CH;
        float var = SS / NELEM_PER_CH - mean * mean;
        ws[0 + ch] = mean;
        ws[512 + ch] = rsqrtf(var + 1e-5f);
    }
}

__global__ __launch_bounds__(1024) void caps_fold(const float* __restrict__ w,
                                                  const float* __restrict__ bias,
                                                  float* __restrict__ ws) {
    const int c = blockIdx.x;
    const int t = threadIdx.x;
    const int o = t >> 5;
    const int i = t & 31;
    const float mean = ws[c * 32 + i];
    const float rstd = ws[512 + c * 32 + i];
    const float wv = w[c * 1024 + t] * rstd;
    ws[WS_WP + c * 1024 + t] = wv;
    float prod = wv * mean;
#pragma unroll
    for (int off = 16; off > 0; off >>= 1) prod += __shfl_xor(prod, off);
    if (i == 0) ws[WS_BP + c * 32 + o] = bias[c * 32 + o] - prod;
}

__global__ __launch_bounds__(256) void caps_main(const float* __restrict__ x,
                                                 const float* __restrict__ ws,
                                                 float* __restrict__ out) {
    const int hw = blockIdx.x * 256 + threadIdx.x;
    const int c = blockIdx.y;
    const int n = blockIdx.z;
    const size_t base = (((size_t)n * 16 + c) * 32) * 1024 + hw;
    const float* __restrict__ Wc = ws + WS_WP + c * 1024;
    const float* __restrict__ b2 = ws + WS_BP + c * 32;
    float xv[32];
#pragma unroll
    for (int i = 0; i < 32; ++i) xv[i] = x[base + (size_t)i * 1024];
#pragma unroll 4
    for (int o = 0; o < 32; ++o) {
        const float* __restrict__ wr = Wc + o * 32;
        float p0 = 0.f, p1 = 0.f, p2 = 0.f, p3 = 0.f;
#pragma unroll
        for (int i = 0; i < 32; i += 4) {
            p0 += wr[i + 0] * xv[i + 0];
            p1 += wr[i + 1] * xv[i + 1];
            p2 += wr[i + 2] * xv[i + 2];
            p3 += wr[i + 3] * xv[i + 3];
        }
        __builtin_nontemporal_store(b2[o] + ((p0 + p1) + (p2 + p3)),
                                    out + base + (size_t)o * 1024);
    }
}

extern "C" void kernel_launch(void* const* d_in, const int* in_sizes, int n_in,
                              void* d_out, int out_size, void* d_ws, size_t ws_size,
                              hipStream_t stream) {
    const float* x    = (const float*)d_in[0];
    const float* w    = (const float*)d_in[1];
    const float* bias = (const float*)d_in[2];
    float* out = (float*)d_out;
    float* ws  = (float*)d_ws;
    int* bar   = (int*)(ws + WS_BAR);

    // Host-side occupancy query (capture-safe: no stream interaction).
    // The persistent kernel is only launched with a grid PROVEN co-resident.
    int maxPerCU = 0;
    hipError_t qerr = hipOccupancyMaxActiveBlocksPerMultiprocessor(
        &maxPerCU, (const void*)caps_all, 256, 0);
    int G = 0;
    if (qerr == hipSuccess && maxPerCU > 0) {
        const long cap = (long)maxPerCU * 256;   // 256 CUs
        if      (cap >= 1536) G = 1536;
        else if (cap >= 1024) G = 1024;
        else if (cap >=  512) G = 512;
    }

    if (G > 0 && ws_size >= (WS_BAR + 16) * sizeof(float)) {
        const int J = G >> 9;                    // blocks per channel in phase 1
        bar_init<<<1, 64, 0, stream>>>(bar);
        caps_all<<<G, 256, 0, stream>>>(x, w, bias, out, ws, bar, J, G);
        return;
    }

    // fallback: proven 3-kernel path (R5, 74.8 us)
    caps_stats<<<512, 256, 0, stream>>>(x, ws);
    caps_fold<<<16, 1024, 0, stream>>>(w, bias, ws);
    caps_main<<<dim3(4, 16, 64), 256, 0, stream>>>(x, ws, out);
}

// Round 10
// 79.592 us; speedup vs baseline: 5.5499x; 4.4053x over previous
//
#include <hip/hip_runtime.h>

// Caps_BN: BatchNorm2d (training stats, affine=False) + grouped 1x1 conv (16 caps
// of 32x32) + bias, folded: out = (W*rstd) @ x + (bias - (W*rstd) @ mean).
// x (64, 512, 32, 32) f32.
//
// 3-kernel structure (no global sync — R8 proved grid.sync is not capture-safe;
// R9 proved software barriers cost ~500us in atomic contention):
//   caps_stats: per-channel mean/rstd        (~21 us, HBM floor)
//   caps_fold:  W'=W*rstd, b'=bias-W'@mean   (~2 us)
//   caps_main:  out = W' @ x + b'            (target ~30-38 us)
//
// ws layout (floats):
//   [0, 512)        mean per channel
//   [512, 1024)     rstd per channel
//   [1024, 17408)   W' folded weight (c, o, i)
//   [17408, 17920)  b' folded bias (c, o)
//
// Lessons encoded:
//  - NEVER set the min-waves arg of __launch_bounds__: (256,6) forced VGPR=40 +
//    scratch spills (R4 113us, R6 440us). Plain (256) measured VGPR=52 clean.
//  - per-thread live state ~<= 100 VGPR is safe; 128+ floats spills (R2).
//  - xv[32] + 4 independent partial sums per o = proven spill-free, ILP-clean
//    (R1's single 32-deep chain was 50% VALUBusy; R5's 4 partials fixed it).
//  - scalar 4B/lane loads/stores = exactly 1.0x WRITE_SIZE (R1/R5/R9).
//  - nt stores keep out from evicting L3-resident x (R9: FETCH 131.5 MB total).
//  - R9 measured phase3-equivalent at ~40us VALU-issue-bound with 1-tile blocks;
//    this version adds cross-quarter prefetch (xn buffer) for in-wave ILP.

#define NELEM_PER_CH 65536.0f
#define WS_WP   1024
#define WS_BP   17408

__global__ __launch_bounds__(256) void caps_stats(const float* __restrict__ x,
                                                  float* __restrict__ ws) {
    const int ch = blockIdx.x;      // 0..511
    const int tid = threadIdx.x;    // 0..255
    const float4* __restrict__ x4 = (const float4*)x;

    float s = 0.f, ss = 0.f;
#pragma unroll 4
    for (int n = 0; n < 64; ++n) {
        float4 v = x4[((size_t)n * 512 + ch) * 256 + tid];
        s  += v.x + v.y + v.z + v.w;
        ss += v.x * v.x + v.y * v.y + v.z * v.z + v.w * v.w;
    }
#pragma unroll
    for (int off = 32; off > 0; off >>= 1) {
        s  += __shfl_down(s, off);
        ss += __shfl_down(ss, off);
    }
    __shared__ float red[4][2];
    if ((tid & 63) == 0) { red[tid >> 6][0] = s; red[tid >> 6][1] = ss; }
    __syncthreads();
    if (tid == 0) {
        float S = 0.f, SS = 0.f;
#pragma unroll
        for (int k = 0; k < 4; ++k) { S += red[k][0]; SS += red[k][1]; }
        float mean = S / NELEM_PER_CH;
        float var = SS / NELEM_PER_CH - mean * mean;
        ws[ch] = mean;
        ws[512 + ch] = rsqrtf(var + 1e-5f);
    }
}

__global__ __launch_bounds__(1024) void caps_fold(const float* __restrict__ w,
                                                  const float* __restrict__ bias,
                                                  float* __restrict__ ws) {
    const int c = blockIdx.x;
    const int t = threadIdx.x;
    const int o = t >> 5;
    const int i = t & 31;
    const float mean = ws[c * 32 + i];
    const float rstd = ws[512 + c * 32 + i];
    const float wv = w[c * 1024 + t] * rstd;
    ws[WS_WP + c * 1024 + t] = wv;           // W'[c][o][i]
    float prod = wv * mean;
#pragma unroll
    for (int off = 16; off > 0; off >>= 1) prod += __shfl_xor(prod, off);
    if (i == 0) ws[WS_BP + c * 32 + o] = bias[c * 32 + o] - prod;
}

// Main: grid (16, 64) = (c, n); 1024 blocks, 4/CU, all resident. Each block does
// its tile's 4 hw-quarters with double-buffered x prefetch across quarters.
__global__ __launch_bounds__(256) void caps_main(const float* __restrict__ x,
                                                 const float* __restrict__ ws,
                                                 float* __restrict__ out) {
    const int c = blockIdx.x;
    const int n = blockIdx.y;
    const int t = threadIdx.x;                         // 0..255

    const size_t tile = (((size_t)n * 16 + c) * 32) * 1024;
    const float* __restrict__ xt = x + tile + t;
    float* __restrict__ ot = out + tile + t;
    const float* __restrict__ Wc = ws + WS_WP + c * 1024;   // block-uniform
    const float* __restrict__ b2 = ws + WS_BP + c * 32;

    float xv[32], xn[32];
#pragma unroll
    for (int i = 0; i < 32; ++i) xv[i] = xt[(size_t)i * 1024];   // q=0

    for (int q = 0; q < 4; ++q) {
        // prefetch next quarter while this quarter computes
        if (q < 3) {
#pragma unroll
            for (int i = 0; i < 32; ++i)
                xn[i] = xt[(size_t)i * 1024 + (q + 1) * 256];
        }

        const size_t obase = (size_t)q * 256;
#pragma unroll 4
        for (int o = 0; o < 32; ++o) {
            const float* __restrict__ wr = Wc + o * 32;         // s_load rows
            float p0 = 0.f, p1 = 0.f, p2 = 0.f, p3 = 0.f;
#pragma unroll
            for (int i = 0; i < 32; i += 4) {
                p0 += wr[i + 0] * xv[i + 0];
                p1 += wr[i + 1] * xv[i + 1];
                p2 += wr[i + 2] * xv[i + 2];
                p3 += wr[i + 3] * xv[i + 3];
            }
            __builtin_nontemporal_store(b2[o] + ((p0 + p1) + (p2 + p3)),
                                        ot + obase + (size_t)o * 1024);
        }

        if (q < 3) {
#pragma unroll
            for (int i = 0; i < 32; ++i) xv[i] = xn[i];
        }
    }
}

extern "C" void kernel_launch(void* const* d_in, const int* in_sizes, int n_in,
                              void* d_out, int out_size, void* d_ws, size_t ws_size,
                              hipStream_t stream) {
    const float* x    = (const float*)d_in[0];
    const float* w    = (const float*)d_in[1];
    const float* bias = (const float*)d_in[2];
    float* out = (float*)d_out;
    float* ws  = (float*)d_ws;

    caps_stats<<<512, 256, 0, stream>>>(x, ws);
    caps_fold<<<16, 1024, 0, stream>>>(w, bias, ws);
    caps_main<<<dim3(16, 64), 256, 0, stream>>>(x, ws, out);
}